// Round 2
// baseline (552.259 us; speedup 1.0000x reference)
//
#include <hip/hip_runtime.h>
#include <math.h>

#define Bsz    8
#define Cdim   256
#define Ssp    8192      // D*H*W = 8*32*32
#define Npts   65536     // B * Ssp
#define NCODES 1024
#define PTS    64        // points per block
#define CT     64        // code tile
#define KC     64        // k-chunk of C staged per step
#define BETA   0.25f

// ---------------- embed norms ----------------
__global__ __launch_bounds__(256) void enorm_kernel(const float* __restrict__ embed,
                                                    float* __restrict__ enorm) {
    int j = blockIdx.x * 256 + threadIdx.x;
    if (j >= NCODES) return;
    const float4* row = reinterpret_cast<const float4*>(embed + (size_t)j * Cdim);
    float s = 0.f;
#pragma unroll 8
    for (int c4 = 0; c4 < Cdim / 4; ++c4) {
        float4 v = row[c4];
        s += v.x * v.x + v.y * v.y + v.z * v.z + v.w * v.w;
    }
    enorm[j] = s;
}

// ---------------- main fused kernel ----------------
__global__ __launch_bounds__(256, 2) void vq_main(const float* __restrict__ z,
                                                  const float* __restrict__ embed,
                                                  const float* __restrict__ enorm,
                                                  float* __restrict__ out_zq,
                                                  float* __restrict__ out_idx,
                                                  float* __restrict__ loss_acc,
                                                  float* __restrict__ counts) {
    // 64KB z-tile + 16KB embed chunk = 80KB -> 2 blocks/CU
    __shared__ __attribute__((aligned(16))) float smem[Cdim * PTS + CT * KC];
    float* zt = smem;                  // [256][64]  c-major, p fast
    float* et = smem + Cdim * PTS;     // [64][64]   j-major, c fast

    const int t  = threadIdx.x;
    const int n0 = blockIdx.x * PTS;
    const int b  = n0 >> 13;           // n0 / 8192
    const int s0 = n0 & 8191;
    const float* zb = z + (size_t)b * Cdim * Ssp + s0;

    // ---- stage z tile: zt[c][p] = z[b][c][s0+p] ----
    {
        const int p4   = (t & 15) * 4;
        const int crow = t >> 4;
#pragma unroll
        for (int it = 0; it < 16; ++it) {
            int c = it * 16 + crow;
            float4 v = *reinterpret_cast<const float4*>(zb + (size_t)c * Ssp + p4);
            *reinterpret_cast<float4*>(&zt[c * PTS + p4]) = v;
        }
    }
    __syncthreads();

    // ---- per-point ||z||^2 (reference includes it; its fp32 magnitude ~256
    //      quantizes the distance grid and decides near-tie argmins) ----
    // partial sums in et scratch (free until first embed stage)
    {
        const int p = t & 63;
        const int q = t >> 6;
        float s = 0.f;
#pragma unroll 8
        for (int c = q * 64; c < q * 64 + 64; ++c) {
            float v = zt[c * PTS + p];
            s += v * v;
        }
        et[q * 64 + p] = s;
    }
    __syncthreads();

    const int pg = t & 15, jg = t >> 4;
    const int p0 = pg * 4, j0 = jg * 4;

    float zn[4];
#pragma unroll
    for (int i = 0; i < 4; ++i) {
        int p = p0 + i;
        zn[i] = ((et[p] + et[64 + p]) + et[128 + p]) + et[192 + p];
    }
    // NOTE: ulp-level differences in zn vs the reference's pairwise sum shift
    // all codes of a row uniformly (same binade) and cannot reorder the argmin.

    float bestv[4] = {3.0e38f, 3.0e38f, 3.0e38f, 3.0e38f};
    int   besti[4] = {0, 0, 0, 0};

    for (int jt = 0; jt < NCODES / CT; ++jt) {
        const int J0 = jt * CT;
        float acc[4][4];
#pragma unroll
        for (int i = 0; i < 4; ++i)
#pragma unroll
            for (int k = 0; k < 4; ++k) acc[i][k] = 0.f;

        for (int ks = 0; ks < Cdim / KC; ++ks) {
            const int cc0 = ks * KC;
            __syncthreads();   // protect et (readers done) before overwrite
            {
                const int cc4 = (t & 15) * 4;
                const int jr  = t >> 4;
#pragma unroll
                for (int jj = 0; jj < 4; ++jj) {
                    int j = jj * 16 + jr;
                    float4 v = *reinterpret_cast<const float4*>(
                        embed + (size_t)(J0 + j) * Cdim + cc0 + cc4);
                    *reinterpret_cast<float4*>(&et[j * KC + cc4]) = v;
                }
            }
            __syncthreads();
#pragma unroll 4
            for (int c = 0; c < KC; ++c) {
                float4 zp = *reinterpret_cast<const float4*>(&zt[(cc0 + c) * PTS + p0]);
                float e0 = et[(j0 + 0) * KC + c];
                float e1 = et[(j0 + 1) * KC + c];
                float e2 = et[(j0 + 2) * KC + c];
                float e3 = et[(j0 + 3) * KC + c];
                acc[0][0] += zp.x * e0; acc[0][1] += zp.x * e1; acc[0][2] += zp.x * e2; acc[0][3] += zp.x * e3;
                acc[1][0] += zp.y * e0; acc[1][1] += zp.y * e1; acc[1][2] += zp.y * e2; acc[1][3] += zp.y * e3;
                acc[2][0] += zp.z * e0; acc[2][1] += zp.z * e1; acc[2][2] += zp.z * e2; acc[2][3] += zp.z * e3;
                acc[3][0] += zp.w * e0; acc[3][1] += zp.w * e1; acc[3][2] += zp.w * e2; acc[3][3] += zp.w * e3;
            }
        }
        // Replicate reference rounding: fl( fl(zn + en) - fl(2*G) ).
        // 2*acc is exact (power-of-2 scale), so FMA contraction is harmless.
#pragma unroll
        for (int k = 0; k < 4; ++k) {
            float en = enorm[J0 + j0 + k];
            int cid = J0 + j0 + k;
#pragma unroll
            for (int i = 0; i < 4; ++i) {
                float k1 = zn[i] + en;
                float sc = k1 - 2.0f * acc[i][k];
                if (sc < bestv[i]) { bestv[i] = sc; besti[i] = cid; }  // ascending -> first occurrence
            }
        }
    }

    // ---- cross-thread argmin reduce (16 jg groups per point) ----
    __syncthreads();
    float* rv   = et;                       // 1024 floats
    int*   ri   = (int*)(et + 1024);        // 1024 ints
    int*   idxf = (int*)(et + 2048);        // 64 ints
#pragma unroll
    for (int i = 0; i < 4; ++i) {
        int p = p0 + i;
        rv[p * 16 + jg] = bestv[i];
        ri[p * 16 + jg] = besti[i];
    }
    __syncthreads();
    if (t < PTS) {
        int p = t;
        float bv = rv[p * 16]; int bi = ri[p * 16];
        for (int g = 1; g < 16; ++g) {
            float v = rv[p * 16 + g]; int ii = ri[p * 16 + g];
            if (v < bv || (v == bv && ii < bi)) { bv = v; bi = ii; }
        }
        idxf[p] = bi;
        out_idx[n0 + p] = (float)bi;        // indices as float (d_out is one f32 buffer)
        atomicAdd(&counts[bi], 1.0f);
    }
    __syncthreads();

    // ---- epilogue: z_q write (coalesced over p) + commitment loss ----
    float lsum = 0.f;
    {
        const int p     = t & 63;           // lane
        const int cbase = t >> 6;           // wave id: c range [cbase*64, cbase*64+64)
        const int myidx = idxf[p];
        const float4* erow4 = reinterpret_cast<const float4*>(embed + (size_t)myidx * Cdim);
        float* ob = out_zq + (size_t)b * Cdim * Ssp + s0 + p;
#pragma unroll 4
        for (int pass = 0; pass < 16; ++pass) {
            int c = cbase * 64 + pass * 4;
            float4 e = erow4[c >> 2];
            ob[(size_t)(c + 0) * Ssp] = e.x;
            ob[(size_t)(c + 1) * Ssp] = e.y;
            ob[(size_t)(c + 2) * Ssp] = e.z;
            ob[(size_t)(c + 3) * Ssp] = e.w;
            float d0 = zt[(c + 0) * PTS + p] - e.x;
            float d1 = zt[(c + 1) * PTS + p] - e.y;
            float d2 = zt[(c + 2) * PTS + p] - e.z;
            float d3 = zt[(c + 3) * PTS + p] - e.w;
            lsum += d0 * d0 + d1 * d1 + d2 * d2 + d3 * d3;
        }
    }
#pragma unroll
    for (int off = 32; off > 0; off >>= 1) lsum += __shfl_down(lsum, off, 64);
    if ((t & 63) == 0) atomicAdd(loss_acc, lsum);
}

// ---------------- finalize: loss + perplexity ----------------
__global__ __launch_bounds__(1024) void vq_final(const float* __restrict__ counts,
                                                 const float* __restrict__ loss_acc,
                                                 float* __restrict__ out_loss,
                                                 float* __restrict__ out_perp) {
    __shared__ float red[16];
    int t = threadIdx.x;
    float cnt = counts[t];
    float avg = cnt * (1.0f / (float)Npts);
    float term = avg * logf(avg + 1e-10f);
#pragma unroll
    for (int off = 32; off > 0; off >>= 1) term += __shfl_down(term, off, 64);
    if ((t & 63) == 0) red[t >> 6] = term;
    __syncthreads();
    if (t == 0) {
        float s = 0.f;
        for (int i = 0; i < 16; ++i) s += red[i];
        *out_perp = expf(-s);
        *out_loss = BETA * loss_acc[0] * (1.0f / 16777216.0f);  // mean over N*C
    }
}

extern "C" void kernel_launch(void* const* d_in, const int* in_sizes, int n_in,
                              void* d_out, int out_size, void* d_ws, size_t ws_size,
                              hipStream_t stream) {
    const float* z     = (const float*)d_in[0];
    const float* embed = (const float*)d_in[1];

    float* ws       = (float*)d_ws;
    float* loss_acc = ws;            // [0]
    float* counts   = ws + 64;       // [1024]
    float* enorm    = ws + 2048;     // [1024]

    float* out_zq   = (float*)d_out;                       // 16777216
    float* out_idx  = out_zq + (size_t)Npts * Cdim;        // 65536
    float* out_loss = out_idx + Npts;                      // 1
    float* out_perp = out_loss + 1;                        // 1

    hipMemsetAsync(d_ws, 0, 2048 * sizeof(float), stream); // loss + counts
    enorm_kernel<<<NCODES / 256, 256, 0, stream>>>(embed, enorm);
    vq_main<<<Npts / PTS, 256, 0, stream>>>(z, embed, enorm, out_zq, out_idx,
                                            loss_acc, counts);
    vq_final<<<1, 1024, 0, stream>>>(counts, loss_acc, out_loss, out_perp);
}